// Round 1
// baseline (17359.106 us; speedup 1.0000x reference)
//
#include <hip/hip_runtime.h>
#include <cstdint>
#include <cstddef>

#define NB   32     // batch
#define NTT  2048   // time steps
#define NIN  256    // input size
#define NH   256    // hidden
#define NG   32     // workgroups
#define NLH  8      // h-columns per WG
#define BLOCK 256

typedef __attribute__((ext_vector_type(8))) short    s8v;
typedef __attribute__((ext_vector_type(4))) float    f4v;
typedef __attribute__((ext_vector_type(4))) unsigned u4v;

__device__ __forceinline__ unsigned f2bf_bits(float v) {
    union { float f; unsigned u; } x; x.f = v;
    return (x.u + 0x7FFFu + ((x.u >> 16) & 1u)) >> 16;  // RTNE
}
__device__ __forceinline__ float bfbits2f(unsigned b) {
    union { float f; unsigned u; } x; x.u = b << 16;
    return x.f;
}
__device__ __forceinline__ float u2f(unsigned u) {
    union { float f; unsigned u; } x; x.u = u; return x.f;
}
__device__ __forceinline__ unsigned cvt_pk_bf16(float s0, float s1) {
    unsigned r;
    asm("v_cvt_pk_bf16_f32 %0, %1, %2" : "=v"(r) : "v"(s0), "v"(s1));
    return r;  // lo16 = bf16(s0), hi16 = bf16(s1)
}
__device__ __forceinline__ void split2(float v0, float v1, unsigned& hp, unsigned& lp) {
    hp = cvt_pk_bf16(v0, v1);
    float h0 = u2f(hp << 16);
    float h1 = u2f(hp & 0xFFFF0000u);
    lp = cvt_pk_bf16(v0 - h0, v1 - h1);  // lo compensates hi rounding exactly in fp32
}
__device__ __forceinline__ void split8(f4v a, f4v b, u4v& hw, u4v& lw) {
    unsigned h0,h1,h2,h3,l0,l1,l2,l3;
    split2(a[0], a[1], h0, l0);
    split2(a[2], a[3], h1, l1);
    split2(b[0], b[1], h2, l2);
    split2(b[2], b[3], h3, l3);
    hw = (u4v){h0,h1,h2,h3};
    lw = (u4v){l0,l1,l2,l3};
}

// A/B LDS tiles: [32 rows][512 bf16], XOR-swizzled at 16B-chunk granularity:
// chunk kc of row r lives at byte ((kc ^ (r&7)) << 4).  Every access in this
// kernel is an aligned 16B chunk of 8 consecutive k-elements, so the swizzle
// is bijective per row and breaks the 1024B-row-stride bank conflict (G4).

__global__ __launch_bounds__(BLOCK, 1) void lstm_kernel(
    const float* __restrict__ x,
    const float* __restrict__ Wf, const float* __restrict__ bfp,
    const float* __restrict__ Wi, const float* __restrict__ bip,
    const float* __restrict__ Wo, const float* __restrict__ bop,
    const float* __restrict__ Wc, const float* __restrict__ bcp,
    float* __restrict__ out,
    unsigned short* __restrict__ hbhi,   // [2][32][256] bf16-hi of h (double buffered)
    unsigned short* __restrict__ hblo,   // [2][32][256] bf16-lo of h
    int* __restrict__ arrive)            // [NG] step-arrival flags (poison 0xAA.. < 0 ok)
{
    __shared__ unsigned short AhiM[NB][512];
    __shared__ unsigned short AloM[NB][512];

    const int wg   = blockIdx.x;
    const int tid  = threadIdx.x;
    const int lane = tid & 63;
    const int wv   = tid >> 6;

    // ---------- init: stage this WG's weight slice transposed+split into LDS ----------
    {
        const int lc   = tid >> 3;                 // local z-col 0..31 (gate*8 + lh)
        const int gate = lc >> 3;
        const int col  = wg * NLH + (lc & 7);
        const float* W = (gate == 0) ? Wf : (gate == 1) ? Wi : (gate == 2) ? Wo : Wc;
        const int c0   = (tid & 7) * 8;            // this thread: 8 chunks (64 k-values)
        #pragma unroll
        for (int cj = 0; cj < 8; ++cj) {
            const int kc = c0 + cj;
            const int k0 = kc * 8;
            f4v a, b;
            #pragma unroll
            for (int e = 0; e < 4; ++e) a[e] = W[(size_t)(k0 + e) * NH + col];
            #pragma unroll
            for (int e = 0; e < 4; ++e) b[e] = W[(size_t)(k0 + 4 + e) * NH + col];
            u4v hw, lw;
            split8(a, b, hw, lw);
            *(u4v*)((char*)&AhiM[lc][0] + ((kc ^ (lc & 7)) << 4)) = hw;
            *(u4v*)((char*)&AloM[lc][0] + ((kc ^ (lc & 7)) << 4)) = lw;
        }
    }
    __syncthreads();

    const int mt = wv & 1;   // M-tile (batch rows mt*16..)
    const int nt = wv >> 1;  // N-tile (z-cols nt*16..)

    // ---------- persistent register-resident B fragments (hi+lo) ----------
    s8v bhi[16], blo[16];
    {
        const int brow = nt * 16 + (lane & 15);
        const int bsub = lane >> 4;
        #pragma unroll
        for (int kt = 0; kt < 16; ++kt) {
            const int kc = kt * 4 + bsub;
            bhi[kt] = *(s8v*)((char*)&AhiM[brow][0] + ((kc ^ (brow & 7)) << 4));
            blo[kt] = *(s8v*)((char*)&AloM[brow][0] + ((kc ^ (brow & 7)) << 4));
        }
    }
    __syncthreads();

    // update role: thread = (batch ub, local h-col ulh)
    const int ub   = tid >> 3;
    const int ulh  = tid & 7;
    const int ucol = wg * NLH + ulh;
    const float bias_f = bfp[ucol];
    const float bias_i = bip[ucol];
    const float bias_o = bop[ucol];
    const float bias_c = bcp[ucol];
    float cst = 0.f;

    // staging role: thread = (row sb, 32-element segment sseg)
    const int sb   = tid >> 3;
    const int sseg = tid & 7;

    const int arow = mt * 16 + (lane & 15);
    const int asub = lane >> 4;

    for (int t = 0; t < NTT; ++t) {
        // ---- stage x part (no dependency on barrier) ----
        {
            const float* xp = x + ((size_t)sb * NTT + t) * NIN + sseg * 32;
            #pragma unroll
            for (int j = 0; j < 4; ++j) {
                f4v a = *(const f4v*)(xp + j * 8);
                f4v b = *(const f4v*)(xp + j * 8 + 4);
                u4v hw, lw;
                split8(a, b, hw, lw);
                const int kc = sseg * 4 + j;
                *(u4v*)((char*)&AhiM[sb][0] + ((kc ^ (sb & 7)) << 4)) = hw;
                *(u4v*)((char*)&AloM[sb][0] + ((kc ^ (sb & 7)) << 4)) = lw;
            }
        }
        // ---- grid barrier: wait until all WGs completed step t-1 ----
        if (t > 0) {
            if (wv == 0 && lane < NG) {
                int spins = 0;
                while (__hip_atomic_load(&arrive[lane], __ATOMIC_RELAXED,
                                         __HIP_MEMORY_SCOPE_AGENT) < t) {
                    __builtin_amdgcn_s_sleep(1);
                    if (++spins > (1 << 18)) break;   // safety: fail loud, don't hang
                }
            }
        }
        __syncthreads();
        if (t > 0) __threadfence();   // acquire: invalidate L1/L2, see fresh h

        // ---- stage h part (pre-split bf16 hi/lo, zero VALU) ----
        if (t == 0) {
            const u4v zz = (u4v){0u, 0u, 0u, 0u};
            #pragma unroll
            for (int j = 0; j < 4; ++j) {
                const int kc = 32 + sseg * 4 + j;
                *(u4v*)((char*)&AhiM[sb][0] + ((kc ^ (sb & 7)) << 4)) = zz;
                *(u4v*)((char*)&AloM[sb][0] + ((kc ^ (sb & 7)) << 4)) = zz;
            }
        } else {
            const size_t hb0 = (size_t)(t & 1) * NB * NH + (size_t)sb * NH + sseg * 32;
            #pragma unroll
            for (int j = 0; j < 4; ++j) {
                u4v vh = *(const u4v*)(hbhi + hb0 + j * 8);
                u4v vl = *(const u4v*)(hblo + hb0 + j * 8);
                const int kc = 32 + sseg * 4 + j;
                *(u4v*)((char*)&AhiM[sb][0] + ((kc ^ (sb & 7)) << 4)) = vh;
                *(u4v*)((char*)&AloM[sb][0] + ((kc ^ (sb & 7)) << 4)) = vl;
            }
        }
        __syncthreads();

        // ---- MFMA: z(32x32) = A(32x512) @ B(512x32); hi/lo split, 3 indep chains ----
        f4v acc0 = (f4v){0.f, 0.f, 0.f, 0.f};
        f4v acc1 = acc0, acc2 = acc0;
        #pragma unroll
        for (int kt = 0; kt < 16; ++kt) {
            const int kc = kt * 4 + asub;
            s8v ah = *(s8v*)((char*)&AhiM[arow][0] + ((kc ^ (arow & 7)) << 4));
            s8v al = *(s8v*)((char*)&AloM[arow][0] + ((kc ^ (arow & 7)) << 4));
            acc0 = __builtin_amdgcn_mfma_f32_16x16x32_bf16(ah, bhi[kt], acc0, 0, 0, 0);
            acc1 = __builtin_amdgcn_mfma_f32_16x16x32_bf16(ah, blo[kt], acc1, 0, 0, 0);
            acc2 = __builtin_amdgcn_mfma_f32_16x16x32_bf16(al, bhi[kt], acc2, 0, 0, 0);
        }
        const f4v zv = acc0 + acc1 + acc2;
        __syncthreads();   // all waves done reading A before z aliases onto AloM

        // ---- z exchange via LDS (aliased: bytes 512..639 of each AloM row) ----
        {
            const int zc = nt * 16 + (lane & 15);
            const int rb = mt * 16 + (lane >> 4) * 4;   // C layout: col=l&15, row=(l>>4)*4+j
            #pragma unroll
            for (int j = 0; j < 4; ++j)
                ((float*)((char*)&AloM[rb + j][0] + 512))[zc] = zv[j];
        }
        __syncthreads();

        // ---- gates + state update + h publish ----
        {
            const float* zr = (const float*)((char*)&AloM[ub][0] + 512);
            const float zf = zr[ulh]       + bias_f;
            const float zi = zr[8  + ulh]  + bias_i;
            const float zo = zr[16 + ulh]  + bias_o;
            const float zg = zr[24 + ulh]  + bias_c;
            const float fg = 1.f / (1.f + __expf(-zf));
            const float ig = 1.f / (1.f + __expf(-zi));
            const float og = 1.f / (1.f + __expf(-zo));
            const float gg = tanhf(zg);
            cst = fg * cst + ig * gg;
            const float hv = og * tanhf(cst);
            const size_t ho = (size_t)((t + 1) & 1) * NB * NH + (size_t)ub * NH + ucol;
            const unsigned hb = f2bf_bits(hv);
            hbhi[ho] = (unsigned short)hb;
            hblo[ho] = (unsigned short)f2bf_bits(hv - bfbits2f(hb));
            // output is reverse-time order
            out[((size_t)ub * NTT + (NTT - 1 - t)) * NH + ucol] = hv;
        }
        __threadfence();   // release: flush h (and out) to coherence point
        __syncthreads();
        if (tid == 0)
            __hip_atomic_store(&arrive[wg], t + 1, __ATOMIC_RELEASE,
                               __HIP_MEMORY_SCOPE_AGENT);
    }
}

extern "C" void kernel_launch(void* const* d_in, const int* in_sizes, int n_in,
                              void* d_out, int out_size, void* d_ws, size_t ws_size,
                              hipStream_t stream) {
    (void)in_sizes; (void)n_in; (void)out_size; (void)ws_size;
    const float* x  = (const float*)d_in[0];
    const float* Wf = (const float*)d_in[1];
    const float* bf = (const float*)d_in[2];
    const float* Wi = (const float*)d_in[3];
    const float* bi = (const float*)d_in[4];
    const float* Wo = (const float*)d_in[5];
    const float* bo = (const float*)d_in[6];
    const float* Wc = (const float*)d_in[7];
    const float* bc = (const float*)d_in[8];
    float* out = (float*)d_out;

    unsigned short* hbhi = (unsigned short*)d_ws;          // 2*32*256 ushort = 32 KiB
    unsigned short* hblo = hbhi + 2 * NB * NH;             // 32 KiB
    int* arrive = (int*)(hblo + 2 * NB * NH);              // 128 B (poison < 0 is fine)

    lstm_kernel<<<NG, BLOCK, 0, stream>>>(x, Wf, bf, Wi, bi, Wo, bo, Wc, bc,
                                          out, hbhi, hblo, arrive);
}

// Round 2
// 9744.283 us; speedup vs baseline: 1.7815x; 1.7815x over previous
//
#include <hip/hip_runtime.h>
#include <cstdint>
#include <cstddef>

#define NB   32     // batch
#define NTT  2048   // time steps
#define NIN  256    // input size
#define NH   256    // hidden
#define NG   32     // workgroups
#define NLH  8      // h-columns per WG
#define BLOCK 256

typedef __attribute__((ext_vector_type(8))) short    s8v;
typedef __attribute__((ext_vector_type(4))) float    f4v;
typedef __attribute__((ext_vector_type(4))) unsigned u4v;

__device__ __forceinline__ unsigned f2bf_bits(float v) {
    union { float f; unsigned u; } x; x.f = v;
    return (x.u + 0x7FFFu + ((x.u >> 16) & 1u)) >> 16;  // RTNE
}
__device__ __forceinline__ float bfbits2f(unsigned b) {
    union { float f; unsigned u; } x; x.u = b << 16;
    return x.f;
}
__device__ __forceinline__ float u2f(unsigned u) {
    union { float f; unsigned u; } x; x.u = u; return x.f;
}
__device__ __forceinline__ unsigned cvt_pk_bf16(float s0, float s1) {
    unsigned r;
    asm("v_cvt_pk_bf16_f32 %0, %1, %2" : "=v"(r) : "v"(s0), "v"(s1));
    return r;  // lo16 = bf16(s0), hi16 = bf16(s1)
}
__device__ __forceinline__ void split2(float v0, float v1, unsigned& hp, unsigned& lp) {
    hp = cvt_pk_bf16(v0, v1);
    float h0 = u2f(hp << 16);
    float h1 = u2f(hp & 0xFFFF0000u);
    lp = cvt_pk_bf16(v0 - h0, v1 - h1);
}
__device__ __forceinline__ void split8(f4v a, f4v b, u4v& hw, u4v& lw) {
    unsigned h0,h1,h2,h3,l0,l1,l2,l3;
    split2(a[0], a[1], h0, l0);
    split2(a[2], a[3], h1, l1);
    split2(b[0], b[1], h2, l2);
    split2(b[2], b[3], h3, l3);
    hw = (u4v){h0,h1,h2,h3};
    lw = (u4v){l0,l1,l2,l3};
}

// Coherent (agent-scope, IF$-direct) ops: sc0 sc1 on every cross-WG access.
// No buffer_inv / buffer_wbl2 anywhere — scope is carried per-op.
__device__ __forceinline__ u4v coh_load4(const unsigned* p) {
    u4v v;
    asm volatile("global_load_dwordx4 %0, %1, off sc0 sc1" : "=v"(v) : "v"(p));
    return v;  // NOT valid until a subsequent s_waitcnt vmcnt(0)
}
__device__ __forceinline__ void coh_store1(unsigned* p, unsigned v) {
    asm volatile("global_store_dword %0, %1, off sc0 sc1" :: "v"(p), "v"(v) : "memory");
}
__device__ __forceinline__ int coh_load_int(const int* p) {
    int v;
    asm volatile("global_load_dword %0, %1, off sc0 sc1\n\ts_waitcnt vmcnt(0)"
                 : "=v"(v) : "v"(p) : "memory");
    return v;
}

// A LDS tile: [32 rows][512 bf16] (hi plane + lo plane), 16B-chunk XOR swizzle:
// chunk kc of row r lives at byte ((kc ^ (r&7)) << 4). All accesses are aligned
// 16B chunks, so the swizzle is bijective per row and kills the 1024B-row-stride
// bank conflict. Chunks 0..31 = x part (k 0..255), 32..63 = h part (k 256..511).

__global__ __launch_bounds__(BLOCK, 1) void lstm_kernel(
    const float* __restrict__ x,
    const float* __restrict__ Wf, const float* __restrict__ bfp,
    const float* __restrict__ Wi, const float* __restrict__ bip,
    const float* __restrict__ Wo, const float* __restrict__ bop,
    const float* __restrict__ Wc, const float* __restrict__ bcp,
    float* __restrict__ out,
    unsigned* __restrict__ hpk,          // [2][32][256] packed h: hi | lo<<16
    int* __restrict__ arrive)            // [NG] step-arrival flags (poison < 0 ok)
{
    __shared__ unsigned short AhiM[NB][512];
    __shared__ unsigned short AloM[NB][512];

    const int wg   = blockIdx.x;
    const int tid  = threadIdx.x;
    const int lane = tid & 63;
    const int wv   = tid >> 6;

    // ---------- init: stage this WG's weight slice transposed+split into LDS ----------
    {
        const int lc   = tid >> 3;                 // local z-col 0..31 (gate*8 + lh)
        const int gate = lc >> 3;
        const int col  = wg * NLH + (lc & 7);
        const float* W = (gate == 0) ? Wf : (gate == 1) ? Wi : (gate == 2) ? Wo : Wc;
        const int c0   = (tid & 7) * 8;
        #pragma unroll
        for (int cj = 0; cj < 8; ++cj) {
            const int kc = c0 + cj;
            const int k0 = kc * 8;
            f4v a, b;
            #pragma unroll
            for (int e = 0; e < 4; ++e) a[e] = W[(size_t)(k0 + e) * NH + col];
            #pragma unroll
            for (int e = 0; e < 4; ++e) b[e] = W[(size_t)(k0 + 4 + e) * NH + col];
            u4v hw, lw;
            split8(a, b, hw, lw);
            *(u4v*)((char*)&AhiM[lc][0] + ((kc ^ (lc & 7)) << 4)) = hw;
            *(u4v*)((char*)&AloM[lc][0] + ((kc ^ (lc & 7)) << 4)) = lw;
        }
    }
    __syncthreads();

    const int mt = wv & 1;   // M-tile (batch rows mt*16..)
    const int nt = wv >> 1;  // N-tile (z-cols nt*16..)

    // ---------- persistent register-resident B fragments (hi+lo) ----------
    s8v bhi[16], blo[16];
    {
        const int brow = nt * 16 + (lane & 15);
        const int bsub = lane >> 4;
        #pragma unroll
        for (int kt = 0; kt < 16; ++kt) {
            const int kc = kt * 4 + bsub;
            bhi[kt] = *(s8v*)((char*)&AhiM[brow][0] + ((kc ^ (brow & 7)) << 4));
            blo[kt] = *(s8v*)((char*)&AloM[brow][0] + ((kc ^ (brow & 7)) << 4));
        }
    }
    __syncthreads();

    // update role: thread = (batch ub, local h-col ulh)
    const int ub   = tid >> 3;
    const int ulh  = tid & 7;
    const int ucol = wg * NLH + ulh;
    const float bias_f = bfp[ucol];
    const float bias_i = bip[ucol];
    const float bias_o = bop[ucol];
    const float bias_c = bcp[ucol];
    float cst = 0.f;

    // staging role: thread = (row sb, segment sseg); chunk kc = j*8 + sseg so that
    // simultaneous lanes hit bank group (sseg^sb)&7 -> 2-way (free).
    const int sb   = tid >> 3;
    const int sseg = tid & 7;

    const int arow = mt * 16 + (lane & 15);
    const int asub = lane >> 4;

    for (int t = 0; t < NTT; ++t) {
        // ---- (A) stage x part: no dependency on the grid barrier ----
        {
            const float* xp = x + ((size_t)sb * NTT + t) * NIN;
            #pragma unroll
            for (int j = 0; j < 4; ++j) {
                const int kc = j * 8 + sseg;
                f4v a = *(const f4v*)(xp + kc * 8);
                f4v b = *(const f4v*)(xp + kc * 8 + 4);
                u4v hw, lw;
                split8(a, b, hw, lw);
                *(u4v*)((char*)&AhiM[sb][0] + ((kc ^ (sb & 7)) << 4)) = hw;
                *(u4v*)((char*)&AloM[sb][0] + ((kc ^ (sb & 7)) << 4)) = lw;
            }
        }
        __syncthreads();   // (B1)

        // ---- (C) MFMA x-part (k 0..255), overlaps straggler WGs ----
        f4v acc0 = (f4v){0.f, 0.f, 0.f, 0.f};
        f4v acc1 = acc0, acc2 = acc0;
        #pragma unroll
        for (int kt = 0; kt < 8; ++kt) {
            const int kc = kt * 4 + asub;
            s8v ah = *(s8v*)((char*)&AhiM[arow][0] + ((kc ^ (arow & 7)) << 4));
            s8v al = *(s8v*)((char*)&AloM[arow][0] + ((kc ^ (arow & 7)) << 4));
            acc0 = __builtin_amdgcn_mfma_f32_16x16x32_bf16(ah, bhi[kt], acc0, 0, 0, 0);
            acc1 = __builtin_amdgcn_mfma_f32_16x16x32_bf16(ah, blo[kt], acc1, 0, 0, 0);
            acc2 = __builtin_amdgcn_mfma_f32_16x16x32_bf16(al, bhi[kt], acc2, 0, 0, 0);
        }

        // ---- (D) grid barrier: wait until all WGs completed step t-1 ----
        if (t > 0 && wv == 0 && lane < NG) {
            const int* fp = arrive + lane;
            int spins = 0;
            while (coh_load_int(fp) < t) {
                __builtin_amdgcn_s_sleep(2);
                if (++spins > (1 << 18)) break;   // fail loud, don't hang
            }
        }
        __syncthreads();   // (B2)

        // ---- (E) stage h part (packed coherent load -> v_perm unpack -> LDS) ----
        if (t == 0) {
            const u4v zz = (u4v){0u, 0u, 0u, 0u};
            #pragma unroll
            for (int j = 0; j < 4; ++j) {
                const int kc = 32 + j * 8 + sseg;
                *(u4v*)((char*)&AhiM[sb][0] + ((kc ^ (sb & 7)) << 4)) = zz;
                *(u4v*)((char*)&AloM[sb][0] + ((kc ^ (sb & 7)) << 4)) = zz;
            }
        } else {
            const unsigned* hp = hpk + (size_t)(t & 1) * NB * NH + (size_t)sb * NH;
            u4v wa[4], wb[4];
            #pragma unroll
            for (int j = 0; j < 4; ++j) {
                const int c0 = (j * 8 + sseg) * 8;
                wa[j] = coh_load4(hp + c0);
                wb[j] = coh_load4(hp + c0 + 4);
            }
            asm volatile("s_waitcnt vmcnt(0)"
                         : "+v"(wa[0]), "+v"(wa[1]), "+v"(wa[2]), "+v"(wa[3]),
                           "+v"(wb[0]), "+v"(wb[1]), "+v"(wb[2]), "+v"(wb[3])
                         :: "memory");
            #pragma unroll
            for (int j = 0; j < 4; ++j) {
                const int kc = 32 + j * 8 + sseg;
                u4v hw, lw;
                hw[0] = __builtin_amdgcn_perm(wa[j][1], wa[j][0], 0x05040100u);
                hw[1] = __builtin_amdgcn_perm(wa[j][3], wa[j][2], 0x05040100u);
                hw[2] = __builtin_amdgcn_perm(wb[j][1], wb[j][0], 0x05040100u);
                hw[3] = __builtin_amdgcn_perm(wb[j][3], wb[j][2], 0x05040100u);
                lw[0] = __builtin_amdgcn_perm(wa[j][1], wa[j][0], 0x07060302u);
                lw[1] = __builtin_amdgcn_perm(wa[j][3], wa[j][2], 0x07060302u);
                lw[2] = __builtin_amdgcn_perm(wb[j][1], wb[j][0], 0x07060302u);
                lw[3] = __builtin_amdgcn_perm(wb[j][3], wb[j][2], 0x07060302u);
                *(u4v*)((char*)&AhiM[sb][0] + ((kc ^ (sb & 7)) << 4)) = hw;
                *(u4v*)((char*)&AloM[sb][0] + ((kc ^ (sb & 7)) << 4)) = lw;
            }
        }
        __syncthreads();   // (B3)

        // ---- (F) MFMA h-part (k 256..511) ----
        #pragma unroll
        for (int kt = 8; kt < 16; ++kt) {
            const int kc = kt * 4 + asub;
            s8v ah = *(s8v*)((char*)&AhiM[arow][0] + ((kc ^ (arow & 7)) << 4));
            s8v al = *(s8v*)((char*)&AloM[arow][0] + ((kc ^ (arow & 7)) << 4));
            acc0 = __builtin_amdgcn_mfma_f32_16x16x32_bf16(ah, bhi[kt], acc0, 0, 0, 0);
            acc1 = __builtin_amdgcn_mfma_f32_16x16x32_bf16(ah, blo[kt], acc1, 0, 0, 0);
            acc2 = __builtin_amdgcn_mfma_f32_16x16x32_bf16(al, bhi[kt], acc2, 0, 0, 0);
        }
        const f4v zv = acc0 + acc1 + acc2;
        __syncthreads();   // (B4) all waves done reading h-region before z aliases it

        // ---- (G) z exchange via LDS (bytes 512..639 of each AloM row) ----
        {
            const int zc = nt * 16 + (lane & 15);
            const int rb = mt * 16 + (lane >> 4) * 4;   // C layout: col=l&15, row=(l>>4)*4+j
            #pragma unroll
            for (int j = 0; j < 4; ++j)
                ((float*)((char*)&AloM[rb + j][0] + 512))[zc] = zv[j];
        }
        __syncthreads();   // (B5)

        // ---- (H) gates + state update + h publish (write-through) ----
        {
            const float* zr = (const float*)((char*)&AloM[ub][0] + 512);
            const float zf = zr[ulh]       + bias_f;
            const float zi = zr[8  + ulh]  + bias_i;
            const float zo = zr[16 + ulh]  + bias_o;
            const float zg = zr[24 + ulh]  + bias_c;
            const float fg = 1.f / (1.f + __expf(-zf));
            const float ig = 1.f / (1.f + __expf(-zi));
            const float og = 1.f / (1.f + __expf(-zo));
            const float gg = tanhf(zg);
            cst = fg * cst + ig * gg;
            const float hv = og * tanhf(cst);
            // pack hi|lo<<16 (both RTNE) and write through to the coherence point
            unsigned p0 = cvt_pk_bf16(hv, 0.f);
            float hi_f = u2f(p0 << 16);
            unsigned w  = cvt_pk_bf16(hv, hv - hi_f);
            coh_store1(hpk + (size_t)((t + 1) & 1) * NB * NH + (size_t)ub * NH + ucol, w);
            // output is reverse-time order; plain cached store (flushed at kernel end)
            out[((size_t)ub * NTT + (NTT - 1 - t)) * NH + ucol] = hv;
        }
        asm volatile("s_waitcnt vmcnt(0)" ::: "memory");  // release: own stores drained
        __syncthreads();   // (B6)
        if (tid == 0) {
            unsigned tv = (unsigned)(t + 1);
            coh_store1((unsigned*)(arrive + wg), tv);
        }
    }
}

extern "C" void kernel_launch(void* const* d_in, const int* in_sizes, int n_in,
                              void* d_out, int out_size, void* d_ws, size_t ws_size,
                              hipStream_t stream) {
    (void)in_sizes; (void)n_in; (void)out_size; (void)ws_size;
    const float* x  = (const float*)d_in[0];
    const float* Wf = (const float*)d_in[1];
    const float* bf = (const float*)d_in[2];
    const float* Wi = (const float*)d_in[3];
    const float* bi = (const float*)d_in[4];
    const float* Wo = (const float*)d_in[5];
    const float* bo = (const float*)d_in[6];
    const float* Wc = (const float*)d_in[7];
    const float* bc = (const float*)d_in[8];
    float* out = (float*)d_out;

    unsigned* hpk = (unsigned*)d_ws;                 // [2][32][256] uint = 64 KiB
    int* arrive = (int*)(hpk + 2 * NB * NH);         // 128 B (poison < 0 is fine)

    lstm_kernel<<<NG, BLOCK, 0, stream>>>(x, Wf, bf, Wi, bi, Wo, bo, Wc, bc,
                                          out, hpk, arrive);
}